// Round 1
// baseline (359.643 us; speedup 1.0000x reference)
//
#include <hip/hip_runtime.h>

// Problem constants (match reference)
#define N_TOKENS 16384
#define IN_F 1024
#define OUT_F 1024
#define NB 256      // sparse blocks
#define BH 32
#define BW 32
#define NRB 32      // OUT_F / BH
#define T_TILE 16   // tokens per workgroup (R4: halved from 32 -> 4 WGs/CU)
#define NW 8        // waves per workgroup (512 threads)
#define XS_STRIDE 1040           // shorts/row; dword stride 520 == 8 (mod 32) -> 0 bank conflicts (R3 measured)
#define SCHED_ALLOC 304          // 288 max real + <=8 wave-pads + >=4 overread slots
#define WF_SLOT_SHORTS 1024      // per entry: 2 col-half frags x 64 lanes x 8 bf16 = 2048 B
#define FLUSH_BIT (1 << 10)

// Workspace layout (bytes). Total ~625 KB.
#define WS_WF_BYTES   (SCHED_ALLOC * WF_SLOT_SHORTS * 2)   // 622592
#define WS_SCHED_OFF  WS_WF_BYTES                           // int[SCHED_ALLOC]
#define WS_POS_OFF    (WS_SCHED_OFF + SCHED_ALLOC * 4)      // int[NB]
#define WS_WSTART_OFF (WS_POS_OFF + NB * 4)                 // int[NW+1]

typedef short short8 __attribute__((ext_vector_type(8)));   // MFMA A/B frag (8 bf16)
typedef float float4v __attribute__((ext_vector_type(4)));  // MFMA C/D frag

// fp32 -> bf16 round-to-nearest-even (inputs finite)
__device__ __forceinline__ short f2bf(float f) {
    unsigned u = __builtin_bit_cast(unsigned, f);
    u += 0x7fffu + ((u >> 16) & 1u);
    return (short)(u >> 16);
}

// ---------------------------------------------------------------------------
// Prep 1 (256 thr): schedule with COUNT-BALANCED row->wave mapping (R4).
// Rows ranked by entry count desc (parallel rank, ties by index), assigned to
// waves in snake order (0..7,7..0,...) -> per-wave totals balanced to within
// a couple entries (old r%8 mapping had systematic ~25% tail in EVERY WG).
// Each wave's segment: rows in rank order, entries contiguous per row
// (intra-row order nondeterministic -> fp sum order only). Entry pack:
// bits[4:0]=c, bits[9:5]=r, bit[10]=flush. Segments padded to EVEN length
// with no-flush pad entries (after the wave's final flush -> never stored).
// Empty rows get a flush-only entry with a zeroed wf slot. Tail overread
// slots zeroed.
// ---------------------------------------------------------------------------
__global__ void prep_sched_kernel(const int* __restrict__ brow, const int* __restrict__ bcol,
                                  int* __restrict__ sched, int* __restrict__ pos_of,
                                  int* __restrict__ wstart, short* __restrict__ wf)
{
    __shared__ int cnt[NRB], start[NRB], cur[NRB];
    __shared__ int eff[NRB], rnk[NRB], wv[NRB], off[NRB];
    __shared__ int wtot[NW], pw[NW + 1];
    const int tid = threadIdx.x;   // 256 threads, one per sparse block
    if (tid < NRB) { cnt[tid] = 0; cur[tid] = 0; }
    __syncthreads();
    const int r = brow[tid];
    const int c = bcol[tid];
    atomicAdd(&cnt[r], 1);
    __syncthreads();
    if (tid < NRB) eff[tid] = cnt[tid] ? cnt[tid] : 1;
    __syncthreads();
    if (tid < NRB) {               // rank by eff desc, ties by index -> bijective
        const int e_ = eff[tid];
        int rk = 0;
        for (int j = 0; j < NRB; ++j) {
            const int ej = eff[j];
            if (ej > e_ || (ej == e_ && j < tid)) ++rk;
        }
        rnk[tid] = rk;
        const int s8 = rk & 7, dir = (rk >> 3) & 1;
        wv[tid] = dir ? (7 - s8) : s8;     // snake: 4 rows/wave, balanced totals
    }
    __syncthreads();
    if (tid < NRB) {               // offset within wave = eff-sum of lower-ranked same-wave rows
        const int w = wv[tid], rk = rnk[tid];
        int o = 0;
        for (int j = 0; j < NRB; ++j)
            if (wv[j] == w && rnk[j] < rk) o += eff[j];
        off[tid] = o;
    }
    if (tid >= NRB && tid < NRB + NW) {    // per-wave raw totals
        const int w = tid - NRB;
        int t = 0;
        for (int j = 0; j < NRB; ++j) if (wv[j] == w) t += eff[j];
        wtot[w] = t;
    }
    __syncthreads();
    if (tid == 0) {                // padded prefix + tail overread slots
        int ws = 0;
        for (int w = 0; w < NW; ++w) { pw[w] = ws; ws += (wtot[w] + 1) & ~1; }
        pw[NW] = ws;
        for (int q = 0; q < 8; ++q) sched[ws + q] = 0;
    }
    __syncthreads();
    if (tid < NRB) start[tid] = pw[wv[tid]] + off[tid];
    if (tid < NW) {
        wstart[tid] = pw[tid];
        if (wtot[tid] & 1) sched[pw[tid] + wtot[tid]] = 0;   // pad entry, no flush
    }
    if (tid == NW) wstart[NW] = pw[NW];
    __syncthreads();
    const int slot = atomicAdd(&cur[r], 1);
    const int pos = start[r] + slot;
    sched[pos] = c | (r << 5) | ((slot == cnt[r] - 1) ? FLUSH_BIT : 0);
    pos_of[tid] = pos;
    if (tid < NRB && cnt[tid] == 0) {       // empty-row fallback (bias still written)
        sched[start[tid]] = (tid << 5) | FLUSH_BIT;
        int4 z = {0, 0, 0, 0};
        int4* dst = (int4*)(wf + (size_t)start[tid] * WF_SLOT_SHORTS);
        for (int q = 0; q < WF_SLOT_SHORTS / 8; ++q) dst[q] = z;
    }
}

// ---------------------------------------------------------------------------
// Prep 2: W fp32 -> bf16 B-fragments in SCHEDULE order.
// B[k=quad*8+j][n=oh*16+l16] = W[b][oh*16+l16][quad*8+j]
// at wf[pos*1024 + oh*512 + lane*8 + j].
// ---------------------------------------------------------------------------
__global__ void prep_w_kernel(const float* __restrict__ wd, const int* __restrict__ pos_of,
                              short* __restrict__ wf)
{
    const int g = blockIdx.x * blockDim.x + threadIdx.x;  // 32768 threads
    const int lane = g & 63;
    const int oh = (g >> 6) & 1;
    const int b = g >> 7;
    const int l16 = lane & 15, quad = lane >> 4;
    const int pos = pos_of[b];
    const float* src = wd + (size_t)b * (BH * BW) + (oh * 16 + l16) * BW + quad * 8;
    const float4 w0 = *(const float4*)src;
    const float4 w1 = *(const float4*)(src + 4);
    short8 o;
    o[0] = f2bf(w0.x); o[1] = f2bf(w0.y); o[2] = f2bf(w0.z); o[3] = f2bf(w0.w);
    o[4] = f2bf(w1.x); o[5] = f2bf(w1.y); o[6] = f2bf(w1.z); o[7] = f2bf(w1.w);
    *(short8*)(wf + (size_t)pos * WF_SLOT_SHORTS + oh * 512 + lane * 8) = o;
}

// ---------------------------------------------------------------------------
// Main (R4): 1024 WGs x 512 thr (8 waves), LDS ~38.6 KB -> 4 WGs/CU =
// 32 waves/CU (needs VGPR<=64, enforced by __launch_bounds__(512,8)).
// WG owns 16 tokens (ONE token-group) -> 2 MFMAs/entry into 2 accumulators.
// Wave w processes its balanced contiguous schedule segment; wf prefetch at
// distance 2 pairs, A-frag & sched prefetch at 1 pair. Prologue (segment
// bounds, first 4 entries, 8 wf frags) issued BEFORE x staging so its L2
// latency hides under the HBM staging burst. Bias staged to LDS -> flush is
// row-agnostic (required by balanced row->wave map).
// ---------------------------------------------------------------------------
__global__ __launch_bounds__(512, 8) void spmm_main_kernel(
    const float* __restrict__ x, const float* __restrict__ bias,
    const short* __restrict__ wf, const int* __restrict__ sched_g,
    const int* __restrict__ wstart_g, float* __restrict__ out)
{
    __shared__ short xs[T_TILE * XS_STRIDE];   // 33280 B
    __shared__ float sbias[OUT_F];             // 4096 B
    __shared__ int ssched[SCHED_ALLOC];        // 1216 B

    const int tid = threadIdx.x;
    const int n0 = blockIdx.x * T_TILE;
    const int lane = tid & 63;
    const int wave = tid >> 6;         // 0..7
    const int l16 = lane & 15, quad = lane >> 4;

    // ---- prologue loads issued before staging (latency overlap) ----
    const int s = wstart_g[wave];
    const int e = wstart_g[wave + 1];  // even length
    int e0 = sched_g[s], e1 = sched_g[s + 1];
    int e2 = sched_g[s + 2], e3 = sched_g[s + 3];   // pads+overread make this safe
    const short* wfl = wf + lane * 8;
    short8 cwA0 = *(const short8*)(wfl + (size_t)s * WF_SLOT_SHORTS);
    short8 cwB0 = *(const short8*)(wfl + (size_t)s * WF_SLOT_SHORTS + 512);
    short8 cwA1 = *(const short8*)(wfl + (size_t)(s + 1) * WF_SLOT_SHORTS);
    short8 cwB1 = *(const short8*)(wfl + (size_t)(s + 1) * WF_SLOT_SHORTS + 512);
    short8 nwA0 = *(const short8*)(wfl + (size_t)(s + 2) * WF_SLOT_SHORTS);
    short8 nwB0 = *(const short8*)(wfl + (size_t)(s + 2) * WF_SLOT_SHORTS + 512);
    short8 nwA1 = *(const short8*)(wfl + (size_t)(s + 3) * WF_SLOT_SHORTS);
    short8 nwB1 = *(const short8*)(wfl + (size_t)(s + 3) * WF_SLOT_SHORTS + 512);

    // Stage x tile -> LDS bf16: 4 rows/iter, 128 thr/row x 8 cols (coalesced
    // dwordx4 pairs), short8 stores, conflict-free stride.
    {
        const int tr = tid >> 7;       // 0..3
        const int tc = tid & 127;      // col octet
        const float* xp = x + (size_t)(n0 + tr) * IN_F + tc * 8;
        short* sp = xs + tr * XS_STRIDE + tc * 8;
#pragma unroll
        for (int it = 0; it < T_TILE / 4; ++it) {
            const float4 a = *(const float4*)xp;
            const float4 b = *(const float4*)(xp + 4);
            short8 sv;
            sv[0] = f2bf(a.x); sv[1] = f2bf(a.y); sv[2] = f2bf(a.z); sv[3] = f2bf(a.w);
            sv[4] = f2bf(b.x); sv[5] = f2bf(b.y); sv[6] = f2bf(b.z); sv[7] = f2bf(b.w);
            *(short8*)sp = sv;
            xp += 4 * IN_F;
            sp += 4 * XS_STRIDE;
        }
    }
    if (tid < SCHED_ALLOC) ssched[tid] = sched_g[tid];
    if (tid < OUT_F / 4) *(float4*)(sbias + tid * 4) = *(const float4*)(bias + tid * 4);
    __syncthreads();

    const short* x0 = xs + l16 * XS_STRIDE + quad * 8;
    short8 a0 = *(const short8*)(x0 + (e0 & 31) * BW);
    short8 a1 = *(const short8*)(x0 + (e1 & 31) * BW);

    float4v accA = {0.f, 0.f, 0.f, 0.f};   // cols +0..15
    float4v accB = {0.f, 0.f, 0.f, 0.f};   // cols +16..31
    float* const outb = out + (size_t)(n0 + quad * 4) * OUT_F + l16;

    auto flush = [&](int ev) {
        if (ev & FLUSH_BIT) {              // wave-uniform in practice
            const int rr = (ev >> 5) & 31;
            const int ob = rr * BH;
            const float bv0 = sbias[ob + l16];        // broadcast across quads
            const float bv1 = sbias[ob + 16 + l16];
            float* op = outb + ob;
#pragma unroll
            for (int g = 0; g < 4; ++g) {  // token = quad*4 + g (C/D layout)
                op[(size_t)g * OUT_F]      = accA[g] + bv0;
                op[(size_t)g * OUT_F + 16] = accB[g] + bv1;
            }
            accA = (float4v){0.f, 0.f, 0.f, 0.f};
            accB = (float4v){0.f, 0.f, 0.f, 0.f};
        }
    };

    for (int k = s; k < e; k += 2) {
        // prefetch pair k+4 (wf: distance 2 pairs; pads/overread slots make
        // every access unconditionally in-bounds)
        const int e4 = ssched[k + 4];
        const int e5 = ssched[k + 5];
        const short8 fwA0 = *(const short8*)(wfl + (size_t)(k + 4) * WF_SLOT_SHORTS);
        const short8 fwB0 = *(const short8*)(wfl + (size_t)(k + 4) * WF_SLOT_SHORTS + 512);
        const short8 fwA1 = *(const short8*)(wfl + (size_t)(k + 5) * WF_SLOT_SHORTS);
        const short8 fwB1 = *(const short8*)(wfl + (size_t)(k + 5) * WF_SLOT_SHORTS + 512);
        // A-frags for pair k+2 (LDS, distance 1 pair)
        const short8 na0 = *(const short8*)(x0 + (e2 & 31) * BW);
        const short8 na1 = *(const short8*)(x0 + (e3 & 31) * BW);

        // entry k
        accA = __builtin_amdgcn_mfma_f32_16x16x32_bf16(a0, cwA0, accA, 0, 0, 0);
        accB = __builtin_amdgcn_mfma_f32_16x16x32_bf16(a0, cwB0, accB, 0, 0, 0);
        flush(e0);
        // entry k+1
        accA = __builtin_amdgcn_mfma_f32_16x16x32_bf16(a1, cwA1, accA, 0, 0, 0);
        accB = __builtin_amdgcn_mfma_f32_16x16x32_bf16(a1, cwB1, accB, 0, 0, 0);
        flush(e1);

        // rotate pipeline
        e0 = e2; e1 = e3; e2 = e4; e3 = e5;
        a0 = na0; a1 = na1;
        cwA0 = nwA0; cwB0 = nwB0; cwA1 = nwA1; cwB1 = nwB1;
        nwA0 = fwA0; nwB0 = fwB0; nwA1 = fwA1; nwB1 = fwB1;
    }
}

extern "C" void kernel_launch(void* const* d_in, const int* in_sizes, int n_in,
                              void* d_out, int out_size, void* d_ws, size_t ws_size,
                              hipStream_t stream) {
    const float* x    = (const float*)d_in[0];
    const float* wd   = (const float*)d_in[1];
    const float* bias = (const float*)d_in[2];
    const int* brow   = (const int*)d_in[3];
    const int* bcol   = (const int*)d_in[4];
    float* out = (float*)d_out;

    char* ws = (char*)d_ws;                 // needs ~625 KB
    short* wf   = (short*)ws;
    int* sched  = (int*)(ws + WS_SCHED_OFF);
    int* pos_of = (int*)(ws + WS_POS_OFF);
    int* wstart = (int*)(ws + WS_WSTART_OFF);

    prep_sched_kernel<<<1, 256, 0, stream>>>(brow, bcol, sched, pos_of, wstart, wf);
    prep_w_kernel<<<NB * 128 / 256, 256, 0, stream>>>(wd, pos_of, wf);
    spmm_main_kernel<<<N_TOKENS / T_TILE, 512, 0, stream>>>(x, bias, wf, sched, wstart, out);
}

// Round 4
// 147.921 us; speedup vs baseline: 2.4313x; 2.4313x over previous
//
#include <hip/hip_runtime.h>

// Problem constants (match reference)
#define N_TOKENS 16384
#define IN_F 1024
#define OUT_F 1024
#define NB 256      // sparse blocks
#define BH 32
#define BW 32
#define NRB 32      // OUT_F / BH
#define T_TILE 16   // tokens per workgroup
#define NW 8        // waves per workgroup (512 threads)
#define XS_STRIDE 1040           // shorts/row; dword stride 520 == 8 (mod 32) -> 0 bank conflicts (R3 measured)
#define SCHED_ALLOC 304          // 288 max real + <=8 wave-pads + >=4 overread slots
#define WF_SLOT_SHORTS 1024      // per entry: 2 col-half frags x 64 lanes x 8 bf16 = 2048 B
#define FLUSH_BIT (1 << 10)

// Workspace layout (bytes). Total ~625 KB.
#define WS_WF_BYTES   (SCHED_ALLOC * WF_SLOT_SHORTS * 2)   // 622592
#define WS_SCHED_OFF  WS_WF_BYTES                           // int[SCHED_ALLOC]
#define WS_POS_OFF    (WS_SCHED_OFF + SCHED_ALLOC * 4)      // int[NB]
#define WS_WSTART_OFF (WS_POS_OFF + NB * 4)                 // int[NW+1]

typedef short short8 __attribute__((ext_vector_type(8)));   // MFMA A/B frag (8 bf16)
typedef float float4v __attribute__((ext_vector_type(4)));  // MFMA C/D frag

// fp32 -> bf16 round-to-nearest-even (inputs finite)
__device__ __forceinline__ short f2bf(float f) {
    unsigned u = __builtin_bit_cast(unsigned, f);
    u += 0x7fffu + ((u >> 16) & 1u);
    return (short)(u >> 16);
}

// ---------------------------------------------------------------------------
// Prep 1 (256 thr): schedule with COUNT-BALANCED row->wave mapping.
// Rows ranked by entry count desc (parallel rank, ties by index), assigned to
// waves in snake order (0..7,7..0,...) -> per-wave totals balanced to within
// a couple entries. Each wave's segment: rows in rank order, entries
// contiguous per row (intra-row order nondeterministic -> fp sum order only).
// Entry pack: bits[4:0]=c, bits[9:5]=r, bit[10]=flush. Segments padded to
// EVEN length with no-flush pad entries (after the wave's final flush ->
// never stored). Empty rows get a flush-only entry with a zeroed wf slot.
// Tail overread slots zeroed.
// ---------------------------------------------------------------------------
__global__ void prep_sched_kernel(const int* __restrict__ brow, const int* __restrict__ bcol,
                                  int* __restrict__ sched, int* __restrict__ pos_of,
                                  int* __restrict__ wstart, short* __restrict__ wf)
{
    __shared__ int cnt[NRB], start[NRB], cur[NRB];
    __shared__ int eff[NRB], rnk[NRB], wv[NRB], off[NRB];
    __shared__ int wtot[NW], pw[NW + 1];
    const int tid = threadIdx.x;   // 256 threads, one per sparse block
    if (tid < NRB) { cnt[tid] = 0; cur[tid] = 0; }
    __syncthreads();
    const int r = brow[tid];
    const int c = bcol[tid];
    atomicAdd(&cnt[r], 1);
    __syncthreads();
    if (tid < NRB) eff[tid] = cnt[tid] ? cnt[tid] : 1;
    __syncthreads();
    if (tid < NRB) {               // rank by eff desc, ties by index -> bijective
        const int e_ = eff[tid];
        int rk = 0;
        for (int j = 0; j < NRB; ++j) {
            const int ej = eff[j];
            if (ej > e_ || (ej == e_ && j < tid)) ++rk;
        }
        rnk[tid] = rk;
        const int s8 = rk & 7, dir = (rk >> 3) & 1;
        wv[tid] = dir ? (7 - s8) : s8;     // snake: 4 rows/wave, balanced totals
    }
    __syncthreads();
    if (tid < NRB) {               // offset within wave = eff-sum of lower-ranked same-wave rows
        const int w = wv[tid], rk = rnk[tid];
        int o = 0;
        for (int j = 0; j < NRB; ++j)
            if (wv[j] == w && rnk[j] < rk) o += eff[j];
        off[tid] = o;
    }
    if (tid >= NRB && tid < NRB + NW) {    // per-wave raw totals
        const int w = tid - NRB;
        int t = 0;
        for (int j = 0; j < NRB; ++j) if (wv[j] == w) t += eff[j];
        wtot[w] = t;
    }
    __syncthreads();
    if (tid == 0) {                // padded prefix + tail overread slots
        int ws = 0;
        for (int w = 0; w < NW; ++w) { pw[w] = ws; ws += (wtot[w] + 1) & ~1; }
        pw[NW] = ws;
        for (int q = 0; q < 8; ++q) sched[ws + q] = 0;
    }
    __syncthreads();
    if (tid < NRB) start[tid] = pw[wv[tid]] + off[tid];
    if (tid < NW) {
        wstart[tid] = pw[tid];
        if (wtot[tid] & 1) sched[pw[tid] + wtot[tid]] = 0;   // pad entry, no flush
    }
    if (tid == NW) wstart[NW] = pw[NW];
    __syncthreads();
    const int slot = atomicAdd(&cur[r], 1);
    const int pos = start[r] + slot;
    sched[pos] = c | (r << 5) | ((slot == cnt[r] - 1) ? FLUSH_BIT : 0);
    pos_of[tid] = pos;
    if (tid < NRB && cnt[tid] == 0) {       // empty-row fallback (bias still written)
        sched[start[tid]] = (tid << 5) | FLUSH_BIT;
        int4 z = {0, 0, 0, 0};
        int4* dst = (int4*)(wf + (size_t)start[tid] * WF_SLOT_SHORTS);
        for (int q = 0; q < WF_SLOT_SHORTS / 8; ++q) dst[q] = z;
    }
}

// ---------------------------------------------------------------------------
// Prep 2: W fp32 -> bf16 B-fragments in SCHEDULE order.
// B[k=quad*8+j][n=oh*16+l16] = W[b][oh*16+l16][quad*8+j]
// at wf[pos*1024 + oh*512 + lane*8 + j].
// ---------------------------------------------------------------------------
__global__ void prep_w_kernel(const float* __restrict__ wd, const int* __restrict__ pos_of,
                              short* __restrict__ wf)
{
    const int g = blockIdx.x * blockDim.x + threadIdx.x;  // 32768 threads
    const int lane = g & 63;
    const int oh = (g >> 6) & 1;
    const int b = g >> 7;
    const int l16 = lane & 15, quad = lane >> 4;
    const int pos = pos_of[b];
    const float* src = wd + (size_t)b * (BH * BW) + (oh * 16 + l16) * BW + quad * 8;
    const float4 w0 = *(const float4*)src;
    const float4 w1 = *(const float4*)(src + 4);
    short8 o;
    o[0] = f2bf(w0.x); o[1] = f2bf(w0.y); o[2] = f2bf(w0.z); o[3] = f2bf(w0.w);
    o[4] = f2bf(w1.x); o[5] = f2bf(w1.y); o[6] = f2bf(w1.z); o[7] = f2bf(w1.w);
    *(short8*)(wf + (size_t)pos * WF_SLOT_SHORTS + oh * 512 + lane * 8) = o;
}

// ---------------------------------------------------------------------------
// Main (R6/R7): 1024 WGs x 512 thr (8 waves), LDS ~38.6 KB,
// launch_bounds(512,6) -> 3 WGs/CU = 24 waves/CU, reg cap ~85.
// WG owns 16 tokens (one token-group) -> 2 MFMAs/entry into 2 accumulators.
// ONE-DEEP wf pipeline (R5 bug fix: R5 loaded fw at k+2 but rotated through a
// two-deep nw stage, leaving cw one pair stale from iter 3 on). Now: prologue
// loads cw = pairs (s,s+1); loop loads fw = pairs (k+2,k+3) and rotates
// cw <- fw directly. Live set ~66 VGPRs -> no spill at the (512,6) cap.
// Schedule entries in SGPRs via readfirstlane (wave-uniform) -> scalar flush
// branch. A-frag & sched prefetch at 1 pair. Prologue loads issued BEFORE x
// staging so their L2 latency hides under the HBM staging burst. Bias in LDS.
// ---------------------------------------------------------------------------
__global__ __launch_bounds__(512, 6) void spmm_main_kernel(
    const float* __restrict__ x, const float* __restrict__ bias,
    const short* __restrict__ wf, const int* __restrict__ sched_g,
    const int* __restrict__ wstart_g, float* __restrict__ out)
{
    __shared__ short xs[T_TILE * XS_STRIDE];   // 33280 B
    __shared__ float sbias[OUT_F];             // 4096 B
    __shared__ int ssched[SCHED_ALLOC];        // 1216 B

    const int tid = threadIdx.x;
    const int n0 = blockIdx.x * T_TILE;
    const int lane = tid & 63;
    const int wave = tid >> 6;         // 0..7
    const int l16 = lane & 15, quad = lane >> 4;

    // ---- prologue loads issued before staging (latency overlap) ----
    const int s = __builtin_amdgcn_readfirstlane(wstart_g[wave]);
    const int e = __builtin_amdgcn_readfirstlane(wstart_g[wave + 1]);  // even length >= 4
    int e0 = __builtin_amdgcn_readfirstlane(sched_g[s]);
    int e1 = __builtin_amdgcn_readfirstlane(sched_g[s + 1]);
    int e2 = __builtin_amdgcn_readfirstlane(sched_g[s + 2]);   // pads+overread make this safe
    int e3 = __builtin_amdgcn_readfirstlane(sched_g[s + 3]);
    const short* wfl = wf + lane * 8;
    short8 cwA0 = *(const short8*)(wfl + (size_t)s * WF_SLOT_SHORTS);
    short8 cwB0 = *(const short8*)(wfl + (size_t)s * WF_SLOT_SHORTS + 512);
    short8 cwA1 = *(const short8*)(wfl + (size_t)(s + 1) * WF_SLOT_SHORTS);
    short8 cwB1 = *(const short8*)(wfl + (size_t)(s + 1) * WF_SLOT_SHORTS + 512);

    // Stage x tile -> LDS bf16: 4 rows/iter, 128 thr/row x 8 cols (coalesced
    // dwordx4 pairs), short8 stores, conflict-free stride.
    {
        const int tr = tid >> 7;       // 0..3
        const int tc = tid & 127;      // col octet
        const float* xp = x + (size_t)(n0 + tr) * IN_F + tc * 8;
        short* sp = xs + tr * XS_STRIDE + tc * 8;
#pragma unroll
        for (int it = 0; it < T_TILE / 4; ++it) {
            const float4 a = *(const float4*)xp;
            const float4 b = *(const float4*)(xp + 4);
            short8 sv;
            sv[0] = f2bf(a.x); sv[1] = f2bf(a.y); sv[2] = f2bf(a.z); sv[3] = f2bf(a.w);
            sv[4] = f2bf(b.x); sv[5] = f2bf(b.y); sv[6] = f2bf(b.z); sv[7] = f2bf(b.w);
            *(short8*)sp = sv;
            xp += 4 * IN_F;
            sp += 4 * XS_STRIDE;
        }
    }
    if (tid < SCHED_ALLOC) ssched[tid] = sched_g[tid];
    if (tid < OUT_F / 4) *(float4*)(sbias + tid * 4) = *(const float4*)(bias + tid * 4);
    __syncthreads();

    const short* x0 = xs + l16 * XS_STRIDE + quad * 8;
    short8 a0 = *(const short8*)(x0 + (e0 & 31) * BW);
    short8 a1 = *(const short8*)(x0 + (e1 & 31) * BW);

    float4v accA = {0.f, 0.f, 0.f, 0.f};   // cols +0..15
    float4v accB = {0.f, 0.f, 0.f, 0.f};   // cols +16..31
    float* const outb = out + (size_t)(n0 + quad * 4) * OUT_F + l16;

    auto flush = [&](int ev) {
        if (ev & FLUSH_BIT) {              // ev in SGPR -> scalar branch
            const int rr = (ev >> 5) & 31;
            const int ob = rr * BH;
            const float bv0 = sbias[ob + l16];        // broadcast across quads
            const float bv1 = sbias[ob + 16 + l16];
            float* op = outb + ob;
#pragma unroll
            for (int g = 0; g < 4; ++g) {  // token = quad*4 + g (C/D layout)
                op[(size_t)g * OUT_F]      = accA[g] + bv0;
                op[(size_t)g * OUT_F + 16] = accB[g] + bv1;
            }
            accA = (float4v){0.f, 0.f, 0.f, 0.f};
            accB = (float4v){0.f, 0.f, 0.f, 0.f};
        }
    };

    for (int k = s; k < e; k += 2) {
        // sched prefetch for pair k+4 (consumed as e2/e3 next iteration)
        const int e4 = __builtin_amdgcn_readfirstlane(ssched[k + 4]);
        const int e5 = __builtin_amdgcn_readfirstlane(ssched[k + 5]);
        // wf prefetch pair (k+2,k+3), consumed NEXT iteration (one-deep;
        // pads/overread slots make every access unconditionally in-bounds;
        // pad/overread W garbage is never stored)
        const short8 fwA0 = *(const short8*)(wfl + (size_t)(k + 2) * WF_SLOT_SHORTS);
        const short8 fwB0 = *(const short8*)(wfl + (size_t)(k + 2) * WF_SLOT_SHORTS + 512);
        const short8 fwA1 = *(const short8*)(wfl + (size_t)(k + 3) * WF_SLOT_SHORTS);
        const short8 fwB1 = *(const short8*)(wfl + (size_t)(k + 3) * WF_SLOT_SHORTS + 512);
        // A-frags for pair k+2 (LDS, distance 1 pair)
        const short8 na0 = *(const short8*)(x0 + (e2 & 31) * BW);
        const short8 na1 = *(const short8*)(x0 + (e3 & 31) * BW);

        // entry k
        accA = __builtin_amdgcn_mfma_f32_16x16x32_bf16(a0, cwA0, accA, 0, 0, 0);
        accB = __builtin_amdgcn_mfma_f32_16x16x32_bf16(a0, cwB0, accB, 0, 0, 0);
        flush(e0);
        // entry k+1
        accA = __builtin_amdgcn_mfma_f32_16x16x32_bf16(a1, cwA1, accA, 0, 0, 0);
        accB = __builtin_amdgcn_mfma_f32_16x16x32_bf16(a1, cwB1, accB, 0, 0, 0);
        flush(e1);

        // rotate pipeline (one-deep)
        e0 = e2; e1 = e3; e2 = e4; e3 = e5;
        a0 = na0; a1 = na1;
        cwA0 = fwA0; cwB0 = fwB0; cwA1 = fwA1; cwB1 = fwB1;
    }
}

extern "C" void kernel_launch(void* const* d_in, const int* in_sizes, int n_in,
                              void* d_out, int out_size, void* d_ws, size_t ws_size,
                              hipStream_t stream) {
    const float* x    = (const float*)d_in[0];
    const float* wd   = (const float*)d_in[1];
    const float* bias = (const float*)d_in[2];
    const int* brow   = (const int*)d_in[3];
    const int* bcol   = (const int*)d_in[4];
    float* out = (float*)d_out;

    char* ws = (char*)d_ws;                 // needs ~625 KB
    short* wf   = (short*)ws;
    int* sched  = (int*)(ws + WS_SCHED_OFF);
    int* pos_of = (int*)(ws + WS_POS_OFF);
    int* wstart = (int*)(ws + WS_WSTART_OFF);

    prep_sched_kernel<<<1, 256, 0, stream>>>(brow, bcol, sched, pos_of, wstart, wf);
    prep_w_kernel<<<NB * 128 / 256, 256, 0, stream>>>(wd, pos_of, wf);
    spmm_main_kernel<<<N_TOKENS / T_TILE, 512, 0, stream>>>(x, bias, wf, sched, wstart, out);
}

// Round 5
// 137.213 us; speedup vs baseline: 2.6211x; 1.0780x over previous
//
#include <hip/hip_runtime.h>

// Problem constants (match reference)
#define N_TOKENS 16384
#define IN_F 1024
#define OUT_F 1024
#define NB 256      // sparse blocks
#define BH 32
#define BW 32
#define NRB 32      // OUT_F / BH
#define T_TILE 32   // tokens per workgroup (R8: back to 32 -> 512B wf per MFMA)
#define NW 8        // waves per workgroup (512 threads)
#define XS_STRIDE 1040           // shorts/row; dword stride 520 == 8 (mod 32) -> 0 bank conflicts (R3 measured)
#define SCHED_ALLOC 304          // 288 max real + <=8 wave-pads + >=4 overread slots
#define WF_SLOT_SHORTS 1024      // per entry: 2 col-half frags x 64 lanes x 8 bf16 = 2048 B
#define FLUSH_BIT (1 << 10)

// Workspace layout (bytes). Total ~625 KB.
#define WS_WF_BYTES   (SCHED_ALLOC * WF_SLOT_SHORTS * 2)   // 622592
#define WS_SCHED_OFF  WS_WF_BYTES                           // int[SCHED_ALLOC]
#define WS_POS_OFF    (WS_SCHED_OFF + SCHED_ALLOC * 4)      // int[NB]
#define WS_WSTART_OFF (WS_POS_OFF + NB * 4)                 // int[NW+1]

typedef short short8 __attribute__((ext_vector_type(8)));   // MFMA A/B frag (8 bf16)
typedef float float4v __attribute__((ext_vector_type(4)));  // MFMA C/D frag

// fp32 -> bf16 round-to-nearest-even (inputs finite)
__device__ __forceinline__ short f2bf(float f) {
    unsigned u = __builtin_bit_cast(unsigned, f);
    u += 0x7fffu + ((u >> 16) & 1u);
    return (short)(u >> 16);
}

// ---------------------------------------------------------------------------
// Prep 1 (256 thr): schedule with COUNT-BALANCED row->wave mapping (proven
// correct in R7). Rows ranked by entry count desc (parallel rank, ties by
// index), assigned to waves in snake order (0..7,7..0,...) -> per-wave totals
// balanced to within a couple entries (the old r%8 mapping gated EVERY WG by
// the same ~+20% longest wave). Each wave's segment: rows in rank order,
// entries contiguous per row (intra-row order nondeterministic -> fp sum
// order only). Entry pack: bits[4:0]=c, bits[9:5]=r, bit[10]=flush. Segments
// padded to EVEN length with no-flush pad entries (consumed after the wave's
// final flush -> never stored). Empty rows get a flush-only entry with a
// zeroed wf slot. Tail overread slots zeroed.
// ---------------------------------------------------------------------------
__global__ void prep_sched_kernel(const int* __restrict__ brow, const int* __restrict__ bcol,
                                  int* __restrict__ sched, int* __restrict__ pos_of,
                                  int* __restrict__ wstart, short* __restrict__ wf)
{
    __shared__ int cnt[NRB], start[NRB], cur[NRB];
    __shared__ int eff[NRB], rnk[NRB], wv[NRB], off[NRB];
    __shared__ int wtot[NW], pw[NW + 1];
    const int tid = threadIdx.x;   // 256 threads, one per sparse block
    if (tid < NRB) { cnt[tid] = 0; cur[tid] = 0; }
    __syncthreads();
    const int r = brow[tid];
    const int c = bcol[tid];
    atomicAdd(&cnt[r], 1);
    __syncthreads();
    if (tid < NRB) eff[tid] = cnt[tid] ? cnt[tid] : 1;
    __syncthreads();
    if (tid < NRB) {               // rank by eff desc, ties by index -> bijective
        const int e_ = eff[tid];
        int rk = 0;
        for (int j = 0; j < NRB; ++j) {
            const int ej = eff[j];
            if (ej > e_ || (ej == e_ && j < tid)) ++rk;
        }
        rnk[tid] = rk;
        const int s8 = rk & 7, dir = (rk >> 3) & 1;
        wv[tid] = dir ? (7 - s8) : s8;     // snake: 4 rows/wave, balanced totals
    }
    __syncthreads();
    if (tid < NRB) {               // offset within wave = eff-sum of lower-ranked same-wave rows
        const int w = wv[tid], rk = rnk[tid];
        int o = 0;
        for (int j = 0; j < NRB; ++j)
            if (wv[j] == w && rnk[j] < rk) o += eff[j];
        off[tid] = o;
    }
    if (tid >= NRB && tid < NRB + NW) {    // per-wave raw totals
        const int w = tid - NRB;
        int t = 0;
        for (int j = 0; j < NRB; ++j) if (wv[j] == w) t += eff[j];
        wtot[w] = t;
    }
    __syncthreads();
    if (tid == 0) {                // padded prefix + tail overread slots
        int ws = 0;
        for (int w = 0; w < NW; ++w) { pw[w] = ws; ws += (wtot[w] + 1) & ~1; }
        pw[NW] = ws;
        for (int q = 0; q < 8; ++q) sched[ws + q] = 0;
    }
    __syncthreads();
    if (tid < NRB) start[tid] = pw[wv[tid]] + off[tid];
    if (tid < NW) {
        wstart[tid] = pw[tid];
        if (wtot[tid] & 1) sched[pw[tid] + wtot[tid]] = 0;   // pad entry, no flush
    }
    if (tid == NW) wstart[NW] = pw[NW];
    __syncthreads();
    const int slot = atomicAdd(&cur[r], 1);
    const int pos = start[r] + slot;
    sched[pos] = c | (r << 5) | ((slot == cnt[r] - 1) ? FLUSH_BIT : 0);
    pos_of[tid] = pos;
    if (tid < NRB && cnt[tid] == 0) {       // empty-row fallback (bias still written)
        sched[start[tid]] = (tid << 5) | FLUSH_BIT;
        int4 z = {0, 0, 0, 0};
        int4* dst = (int4*)(wf + (size_t)start[tid] * WF_SLOT_SHORTS);
        for (int q = 0; q < WF_SLOT_SHORTS / 8; ++q) dst[q] = z;
    }
}

// ---------------------------------------------------------------------------
// Prep 2: W fp32 -> bf16 B-fragments in SCHEDULE order.
// B[k=quad*8+j][n=oh*16+l16] = W[b][oh*16+l16][quad*8+j]
// at wf[pos*1024 + oh*512 + lane*8 + j].
// ---------------------------------------------------------------------------
__global__ void prep_w_kernel(const float* __restrict__ wd, const int* __restrict__ pos_of,
                              short* __restrict__ wf)
{
    const int g = blockIdx.x * blockDim.x + threadIdx.x;  // 32768 threads
    const int lane = g & 63;
    const int oh = (g >> 6) & 1;
    const int b = g >> 7;
    const int l16 = lane & 15, quad = lane >> 4;
    const int pos = pos_of[b];
    const float* src = wd + (size_t)b * (BH * BW) + (oh * 16 + l16) * BW + quad * 8;
    const float4 w0 = *(const float4*)src;
    const float4 w1 = *(const float4*)(src + 4);
    short8 o;
    o[0] = f2bf(w0.x); o[1] = f2bf(w0.y); o[2] = f2bf(w0.z); o[3] = f2bf(w0.w);
    o[4] = f2bf(w1.x); o[5] = f2bf(w1.y); o[6] = f2bf(w1.z); o[7] = f2bf(w1.w);
    *(short8*)(wf + (size_t)pos * WF_SLOT_SHORTS + oh * 512 + lane * 8) = o;
}

// ---------------------------------------------------------------------------
// Main (R8): R3 geometry + balanced schedule. 512 WGs x 512 thr (8 waves),
// LDS ~73.9 KB -> 2 WGs/CU (512 WGs = exactly one full residency, no
// dispatch tail). WG owns 32 tokens (2 token groups); each wf slot feeds 4
// MFMAs (512 B/MFMA -- T=16's 1KB/MFMA doubled L2 traffic and regressed, R7).
// Two-deep wf prefetch (cw/nw + fw at k+4, R3-verified rotation). Schedule
// entries in SGPRs via readfirstlane -> scalar flush branch. Bias in LDS
// (required by balanced arbitrary row order). Prologue (bounds, first 4
// entries, 8 wf frags) issued BEFORE x staging so its L2 latency hides under
// the HBM staging burst.
// ---------------------------------------------------------------------------
__global__ __launch_bounds__(512, 4) void spmm_main_kernel(
    const float* __restrict__ x, const float* __restrict__ bias,
    const short* __restrict__ wf, const int* __restrict__ sched_g,
    const int* __restrict__ wstart_g, float* __restrict__ out)
{
    __shared__ short xs[T_TILE * XS_STRIDE];   // 66560 B
    __shared__ float sbias[OUT_F];             // 4096 B
    __shared__ int ssched[SCHED_ALLOC];        // 1216 B

    const int tid = threadIdx.x;
    const int n0 = blockIdx.x * T_TILE;
    const int lane = tid & 63;
    const int wave = tid >> 6;         // 0..7
    const int l16 = lane & 15, quad = lane >> 4;

    // ---- prologue loads issued before staging (latency overlap) ----
    const int s = __builtin_amdgcn_readfirstlane(wstart_g[wave]);
    const int e = __builtin_amdgcn_readfirstlane(wstart_g[wave + 1]);  // even length >= 4
    int e0 = __builtin_amdgcn_readfirstlane(sched_g[s]);
    int e1 = __builtin_amdgcn_readfirstlane(sched_g[s + 1]);
    int e2 = __builtin_amdgcn_readfirstlane(sched_g[s + 2]);   // pads+overread make this safe
    int e3 = __builtin_amdgcn_readfirstlane(sched_g[s + 3]);
    const short* wfl = wf + lane * 8;
    short8 cwA0 = *(const short8*)(wfl + (size_t)s * WF_SLOT_SHORTS);
    short8 cwB0 = *(const short8*)(wfl + (size_t)s * WF_SLOT_SHORTS + 512);
    short8 cwA1 = *(const short8*)(wfl + (size_t)(s + 1) * WF_SLOT_SHORTS);
    short8 cwB1 = *(const short8*)(wfl + (size_t)(s + 1) * WF_SLOT_SHORTS + 512);
    short8 nwA0 = *(const short8*)(wfl + (size_t)(s + 2) * WF_SLOT_SHORTS);
    short8 nwB0 = *(const short8*)(wfl + (size_t)(s + 2) * WF_SLOT_SHORTS + 512);
    short8 nwA1 = *(const short8*)(wfl + (size_t)(s + 3) * WF_SLOT_SHORTS);
    short8 nwB1 = *(const short8*)(wfl + (size_t)(s + 3) * WF_SLOT_SHORTS + 512);

    // Stage x tile -> LDS bf16: 4 rows/iter, 128 thr/row x 8 cols (coalesced
    // dwordx4 pairs), short8 stores, conflict-free stride.
    {
        const int tr = tid >> 7;       // 0..3
        const int tc = tid & 127;      // col octet
        const float* xp = x + (size_t)(n0 + tr) * IN_F + tc * 8;
        short* sp = xs + tr * XS_STRIDE + tc * 8;
#pragma unroll
        for (int it = 0; it < T_TILE / 4; ++it) {
            const float4 a = *(const float4*)xp;
            const float4 b = *(const float4*)(xp + 4);
            short8 sv;
            sv[0] = f2bf(a.x); sv[1] = f2bf(a.y); sv[2] = f2bf(a.z); sv[3] = f2bf(a.w);
            sv[4] = f2bf(b.x); sv[5] = f2bf(b.y); sv[6] = f2bf(b.z); sv[7] = f2bf(b.w);
            *(short8*)sp = sv;
            xp += 4 * IN_F;
            sp += 4 * XS_STRIDE;
        }
    }
    if (tid < SCHED_ALLOC) ssched[tid] = sched_g[tid];
    if (tid < OUT_F / 4) *(float4*)(sbias + tid * 4) = *(const float4*)(bias + tid * 4);
    __syncthreads();

    const short* x0 = xs + l16 * XS_STRIDE + quad * 8;   // token group 0
    const short* x1 = x0 + 16 * XS_STRIDE;               // token group 1
    short8 a0t0 = *(const short8*)(x0 + (e0 & 31) * BW);
    short8 a0t1 = *(const short8*)(x1 + (e0 & 31) * BW);
    short8 a1t0 = *(const short8*)(x0 + (e1 & 31) * BW);
    short8 a1t1 = *(const short8*)(x1 + (e1 & 31) * BW);

    float4v accA = {0.f, 0.f, 0.f, 0.f};   // tg0, cols +0..15
    float4v accB = {0.f, 0.f, 0.f, 0.f};   // tg0, cols +16..31
    float4v accC = {0.f, 0.f, 0.f, 0.f};   // tg1, cols +0..15
    float4v accD = {0.f, 0.f, 0.f, 0.f};   // tg1, cols +16..31
    float* const outb = out + (size_t)(n0 + quad * 4) * OUT_F + l16;

    auto flush = [&](int ev) {
        if (ev & FLUSH_BIT) {              // ev in SGPR -> scalar branch
            const int rr = (ev >> 5) & 31;
            const int ob = rr * BH;
            const float bv0 = sbias[ob + l16];        // broadcast across quads
            const float bv1 = sbias[ob + 16 + l16];
            float* op0 = outb + ob;
            float* op1 = op0 + (size_t)16 * OUT_F;
#pragma unroll
            for (int g = 0; g < 4; ++g) {  // token = tg*16 + quad*4 + g (C/D layout)
                op0[(size_t)g * OUT_F]      = accA[g] + bv0;
                op0[(size_t)g * OUT_F + 16] = accB[g] + bv1;
                op1[(size_t)g * OUT_F]      = accC[g] + bv0;
                op1[(size_t)g * OUT_F + 16] = accD[g] + bv1;
            }
            accA = (float4v){0.f, 0.f, 0.f, 0.f};
            accB = (float4v){0.f, 0.f, 0.f, 0.f};
            accC = (float4v){0.f, 0.f, 0.f, 0.f};
            accD = (float4v){0.f, 0.f, 0.f, 0.f};
        }
    };

    for (int k = s; k < e; k += 2) {
        // sched prefetch (consumed as e2/e3 next iteration)
        const int e4 = __builtin_amdgcn_readfirstlane(ssched[k + 4]);
        const int e5 = __builtin_amdgcn_readfirstlane(ssched[k + 5]);
        // wf prefetch pair (k+4,k+5): distance 2 pairs (pads/overread slots
        // make every access unconditionally in-bounds; garbage never stored)
        const short8 fwA0 = *(const short8*)(wfl + (size_t)(k + 4) * WF_SLOT_SHORTS);
        const short8 fwB0 = *(const short8*)(wfl + (size_t)(k + 4) * WF_SLOT_SHORTS + 512);
        const short8 fwA1 = *(const short8*)(wfl + (size_t)(k + 5) * WF_SLOT_SHORTS);
        const short8 fwB1 = *(const short8*)(wfl + (size_t)(k + 5) * WF_SLOT_SHORTS + 512);
        // A-frags for pair k+2 (LDS, distance 1 pair)
        const short8 na0t0 = *(const short8*)(x0 + (e2 & 31) * BW);
        const short8 na0t1 = *(const short8*)(x1 + (e2 & 31) * BW);
        const short8 na1t0 = *(const short8*)(x0 + (e3 & 31) * BW);
        const short8 na1t1 = *(const short8*)(x1 + (e3 & 31) * BW);

        // entry k
        accA = __builtin_amdgcn_mfma_f32_16x16x32_bf16(a0t0, cwA0, accA, 0, 0, 0);
        accB = __builtin_amdgcn_mfma_f32_16x16x32_bf16(a0t0, cwB0, accB, 0, 0, 0);
        accC = __builtin_amdgcn_mfma_f32_16x16x32_bf16(a0t1, cwA0, accC, 0, 0, 0);
        accD = __builtin_amdgcn_mfma_f32_16x16x32_bf16(a0t1, cwB0, accD, 0, 0, 0);
        flush(e0);
        // entry k+1
        accA = __builtin_amdgcn_mfma_f32_16x16x32_bf16(a1t0, cwA1, accA, 0, 0, 0);
        accB = __builtin_amdgcn_mfma_f32_16x16x32_bf16(a1t0, cwB1, accB, 0, 0, 0);
        accC = __builtin_amdgcn_mfma_f32_16x16x32_bf16(a1t1, cwA1, accC, 0, 0, 0);
        accD = __builtin_amdgcn_mfma_f32_16x16x32_bf16(a1t1, cwB1, accD, 0, 0, 0);
        flush(e1);

        // rotate pipeline (two-deep, R3-verified)
        e0 = e2; e1 = e3; e2 = e4; e3 = e5;
        a0t0 = na0t0; a0t1 = na0t1; a1t0 = na1t0; a1t1 = na1t1;
        cwA0 = nwA0; cwB0 = nwB0; cwA1 = nwA1; cwB1 = nwB1;
        nwA0 = fwA0; nwB0 = fwB0; nwA1 = fwA1; nwB1 = fwB1;
    }
}

extern "C" void kernel_launch(void* const* d_in, const int* in_sizes, int n_in,
                              void* d_out, int out_size, void* d_ws, size_t ws_size,
                              hipStream_t stream) {
    const float* x    = (const float*)d_in[0];
    const float* wd   = (const float*)d_in[1];
    const float* bias = (const float*)d_in[2];
    const int* brow   = (const int*)d_in[3];
    const int* bcol   = (const int*)d_in[4];
    float* out = (float*)d_out;

    char* ws = (char*)d_ws;                 // needs ~625 KB
    short* wf   = (short*)ws;
    int* sched  = (int*)(ws + WS_SCHED_OFF);
    int* pos_of = (int*)(ws + WS_POS_OFF);
    int* wstart = (int*)(ws + WS_WSTART_OFF);

    prep_sched_kernel<<<1, 256, 0, stream>>>(brow, bcol, sched, pos_of, wstart, wf);
    prep_w_kernel<<<NB * 128 / 256, 256, 0, stream>>>(wd, pos_of, wf);
    spmm_main_kernel<<<N_TOKENS / T_TILE, 512, 0, stream>>>(x, bias, wf, sched, wstart, out);
}